// Round 9
// baseline (281.373 us; speedup 1.0000x reference)
//
#include <hip/hip_runtime.h>
#include <hip/hip_bf16.h>
#include <math.h>

#define NN 131072
#define HD 256

typedef __bf16 bf16;
typedef __attribute__((ext_vector_type(8))) __bf16 bf16x8;
typedef __attribute__((ext_vector_type(4))) __bf16 bf16x4;
typedef __attribute__((ext_vector_type(4))) float f32x4;

__device__ __forceinline__ float silu_f(float x) { return x / (1.f + __expf(-x)); }

__device__ __forceinline__ float bfu2f(unsigned int lo16) {
    unsigned int u = lo16 << 16;
    return __builtin_bit_cast(float, u);
}
__device__ __forceinline__ unsigned short f2bfu(float f) {
    bf16 b = (bf16)f;
    return __builtin_bit_cast(unsigned short, b);
}
__device__ __forceinline__ uint2 pack4(float a, float b, float c, float d) {
    uint2 v;
    v.x = (unsigned int)f2bfu(a) | ((unsigned int)f2bfu(b) << 16);
    v.y = (unsigned int)f2bfu(c) | ((unsigned int)f2bfu(d) << 16);
    return v;
}

// GEMM over 64-row LDS A-tile (stride 264) x packed-B, 2-deep B prefetch.
// SWAP=true: mfma(W,X) -> lane holds (n = 16(4w+c)+4lkhi+q, m = 16r+lrow)
// SWAP=false: mfma(X,W) -> lane holds (m = 16r+4lkhi+q, n = 16(4w+c)+lrow)
template<int KS, bool SWAP>
__device__ __forceinline__ void mmP(const bf16* Xl, int bk0, const bf16x8* __restrict__ Bp,
                                    int wave, int lane, f32x4 acc[4][4]) {
    const int lrow = lane & 15, lkhi = lane >> 4;
    bf16x8 bcur[4], bnxt[4];
    #pragma unroll
    for (int c = 0; c < 4; ++c)
        bcur[c] = Bp[(bk0 * 16 + wave * 4 + c) * 64 + lane];
    #pragma unroll
    for (int ks = 0; ks < KS; ++ks) {
        if (ks + 1 < KS) {
            #pragma unroll
            for (int c = 0; c < 4; ++c)
                bnxt[c] = Bp[((bk0 + ks + 1) * 16 + wave * 4 + c) * 64 + lane];
        }
        bf16x8 a[4];
        #pragma unroll
        for (int r = 0; r < 4; ++r)
            a[r] = *(const bf16x8*)&Xl[(r * 16 + lrow) * 264 + ks * 32 + lkhi * 8];
        #pragma unroll
        for (int c = 0; c < 4; ++c)
            #pragma unroll
            for (int r = 0; r < 4; ++r)
                acc[r][c] = SWAP
                    ? __builtin_amdgcn_mfma_f32_16x16x32_bf16(bcur[c], a[r], acc[r][c], 0, 0, 0)
                    : __builtin_amdgcn_mfma_f32_16x16x32_bf16(a[r], bcur[c], acc[r][c], 0, 0, 0);
        #pragma unroll
        for (int c = 0; c < 4; ++c) bcur[c] = bnxt[c];
    }
}

// extras K-step: X side = EXT[m][0..7] (col0=1, col1=dist) on lkhi==0 lanes, else 0.
template<bool SWAP>
__device__ __forceinline__ void extrasStep(const bf16* EXT, const bf16x8* __restrict__ Bp, int ksx,
                                           int wave, int lane, f32x4 acc[4][4]) {
    const int lrow = lane & 15, lkhi = lane >> 4;
    bf16x8 bext[4];
    #pragma unroll
    for (int c = 0; c < 4; ++c)
        bext[c] = Bp[(ksx * 16 + wave * 4 + c) * 64 + lane];
    bf16x8 zero;
    #pragma unroll
    for (int j = 0; j < 8; ++j) zero[j] = (bf16)0.f;
    #pragma unroll
    for (int r = 0; r < 4; ++r) {
        bf16x8 ae = (lkhi == 0) ? *(const bf16x8*)&EXT[(r * 16 + lrow) * 8] : zero;
        #pragma unroll
        for (int c = 0; c < 4; ++c)
            acc[r][c] = SWAP
                ? __builtin_amdgcn_mfma_f32_16x16x32_bf16(bext[c], ae, acc[r][c], 0, 0, 0)
                : __builtin_amdgcn_mfma_f32_16x16x32_bf16(ae, bext[c], acc[r][c], 0, 0, 0);
    }
}

// ---------------- weight packing (with bias/extra rows appended) ----------------
__device__ __forceinline__ void packGen(const float* __restrict__ W, const float* __restrict__ bias,
                                        const float* __restrict__ extra, int Kreal,
                                        bf16* __restrict__ P, int idx) {
    int j  = idx & 7;
    int ln = (idx >> 3) & 63;
    int cb = (idx >> 9) & 15;
    int ks = idx >> 13;
    int k = ks * 32 + ((ln >> 4) << 3) + j;
    int n = (cb << 4) + (ln & 15);
    float v;
    if (k < Kreal) v = W[k * HD + n];
    else if (k == Kreal) v = bias ? bias[n] : 0.f;
    else if (k == Kreal + 1) v = extra ? extra[n] : 0.f;
    else v = 0.f;
    P[idx] = (bf16)v;
}

__global__ void pack_kernel(const float* __restrict__ ew1, const float* __restrict__ eb1,
                            const float* __restrict__ ew2, const float* __restrict__ eb2,
                            const float* __restrict__ pw1, const float* __restrict__ pb1,
                            const float* __restrict__ nw1, const float* __restrict__ nw2,
                            bf16* __restrict__ ew1p, bf16* __restrict__ ew2p,
                            bf16* __restrict__ pw1p, bf16* __restrict__ nw1p,
                            bf16* __restrict__ nw2p) {
    int t = blockIdx.x * 256 + threadIdx.x;
    if (t < 139264) { packGen(ew1, eb1, ew1 + 512 * HD, 512, ew1p, t); return; }  // 17 ks
    t -= 139264;
    if (t < 73728)  { packGen(ew2, eb2, nullptr, 256, ew2p, t); return; }         // 9 ks
    t -= 73728;
    if (t < 73728)  { packGen(pw1, pb1, nullptr, 256, pw1p, t); return; }         // 9 ks
    t -= 73728;
    if (t < 131072) { packGen(nw1, nullptr, nullptr, 512, nw1p, t); return; }     // 16 ks
    t -= 131072;
    if (t < 65536)  { packGen(nw2, nullptr, nullptr, 256, nw2p, t); return; }     // 8 ks
}

// ---------------- edge kernel ----------------
// 64 edges/block, (256,3), 5 barriers. Swapped GEMMs + folded bias/dist.
// p1,q1 leave as coalesced fragment chunks (uint2); dp fully reduced.
__global__ __launch_bounds__(256, 3) void edge_kernel(
    const float* __restrict__ h, const float* __restrict__ pos,
    const float* __restrict__ pw2,
    const bf16x8* __restrict__ ew1p, const bf16x8* __restrict__ ew2p,
    const bf16x8* __restrict__ pw1p, const bf16x8* __restrict__ nw1p,
    uint2* __restrict__ q1f_g, uint2* __restrict__ p1_g,
    float* __restrict__ dp_g) {
    __shared__ bf16 X[65 * 264];         // h rows -> t1 -> ea (in place)
    __shared__ bf16 EXT[64 * 8];         // [m][0]=1, [m][1]=dist, rest 0
    __shared__ float dp_s[4][64][3];

    const int tid = threadIdx.x;
    const int lane = tid & 63, wave = tid >> 6;
    const int lrow = lane & 15, lkhi = lane >> 4;
    const int e0 = blockIdx.x * 64;

    // stage h rows e0..e0+64 (bf16)
    for (int idx = tid; idx < 65 * 64; idx += 256) {
        int r = idx >> 6, c4 = (idx & 63) << 2;
        int gr = e0 + r;
        float4 v = make_float4(0.f, 0.f, 0.f, 0.f);
        if (gr < NN) v = *(const float4*)&h[(size_t)gr * HD + c4];
        bf16x4 b;
        b[0] = (bf16)v.x; b[1] = (bf16)v.y; b[2] = (bf16)v.z; b[3] = (bf16)v.w;
        *(bf16x4*)&X[r * 264 + c4] = b;
    }
    if (tid < 64) {
        int e = e0 + tid;
        float d = 0.f;
        if (e < NN - 1) {
            float dx = pos[3 * e + 3] - pos[3 * e];
            float dy = pos[3 * e + 4] - pos[3 * e + 1];
            float dz = pos[3 * e + 5] - pos[3 * e + 2];
            d = sqrtf(dx * dx + dy * dy + dz * dz);
        }
        uint2 a, z;
        a.x = (unsigned int)f2bfu(1.0f) | ((unsigned int)f2bfu(d) << 16);
        a.y = 0u; z.x = 0u; z.y = 0u;
        *(uint2*)&EXT[tid * 8] = a;
        *(uint2*)&EXT[tid * 8 + 4] = z;
    }
    // w2l for dp (phase 3a unswapped: n = 16(4w+c)+lrow)
    float w2l[4][3];
    #pragma unroll
    for (int c = 0; c < 4; ++c) {
        int n = (wave * 4 + c) * 16 + lrow;
        #pragma unroll
        for (int x = 0; x < 3; ++x) w2l[c][x] = pw2[n * 3 + x];
    }
    __syncthreads();

    f32x4 acc[4][4];

    // P0: p1 = h @ nw1[:256], swapped -> fragment chunks (global, no barrier)
    #pragma unroll
    for (int r = 0; r < 4; ++r)
        #pragma unroll
        for (int c = 0; c < 4; ++c) acc[r][c] = (f32x4)0.f;
    mmP<8, true>(X, 0, nw1p, wave, lane, acc);
    {
        uint2* w = p1_g + ((size_t)blockIdx.x * 4 + wave) * 1024;
        #pragma unroll
        for (int r = 0; r < 4; ++r)
            #pragma unroll
            for (int c = 0; c < 4; ++c)
                w[(r * 4 + c) * 64 + lane] =
                    pack4(acc[r][c][0], acc[r][c][1], acc[r][c][2], acc[r][c][3]);
    }

    // P1: t1 = silu(edge_feat @ ew1 + eb1 + dist*ew1[512]); 16 data ks (rb) + extras
    #pragma unroll
    for (int r = 0; r < 4; ++r)
        #pragma unroll
        for (int c = 0; c < 4; ++c) acc[r][c] = (f32x4)0.f;
    {
        bf16x8 bcur[4], bnxt[4];
        #pragma unroll
        for (int c = 0; c < 4; ++c)
            bcur[c] = ew1p[(wave * 4 + c) * 64 + lane];
        #pragma unroll
        for (int ks = 0; ks < 16; ++ks) {
            if (ks < 15) {
                #pragma unroll
                for (int c = 0; c < 4; ++c)
                    bnxt[c] = ew1p[((ks + 1) * 16 + wave * 4 + c) * 64 + lane];
            }
            const int rb = (ks >= 8) ? 1 : 0;
            const int kk = ks * 32 + lkhi * 8 - rb * 256;
            bf16x8 a[4];
            #pragma unroll
            for (int r = 0; r < 4; ++r)
                a[r] = *(const bf16x8*)&X[(r * 16 + lrow + rb) * 264 + kk];
            #pragma unroll
            for (int c = 0; c < 4; ++c)
                #pragma unroll
                for (int r = 0; r < 4; ++r)
                    acc[r][c] = __builtin_amdgcn_mfma_f32_16x16x32_bf16(bcur[c], a[r], acc[r][c], 0, 0, 0);
            #pragma unroll
            for (int c = 0; c < 4; ++c) bcur[c] = bnxt[c];
        }
    }
    extrasStep<true>(EXT, ew1p, 16, wave, lane, acc);
    __syncthreads();  // all P0/P1 reads of X done
    #pragma unroll
    for (int r = 0; r < 4; ++r)
        #pragma unroll
        for (int c = 0; c < 4; ++c) {
            int m = 16 * r + lrow;
            int col0 = (wave * 4 + c) * 16 + 4 * lkhi;
            *(uint2*)&X[m * 264 + col0] =
                pack4(silu_f(acc[r][c][0]), silu_f(acc[r][c][1]),
                      silu_f(acc[r][c][2]), silu_f(acc[r][c][3]));
        }
    __syncthreads();

    // P2: ea = t1 @ ew2 + eb2 (folded), swapped
    #pragma unroll
    for (int r = 0; r < 4; ++r)
        #pragma unroll
        for (int c = 0; c < 4; ++c) acc[r][c] = (f32x4)0.f;
    mmP<8, true>(X, 0, ew2p, wave, lane, acc);
    extrasStep<true>(EXT, ew2p, 8, wave, lane, acc);
    __syncthreads();  // all P2 reads done
    #pragma unroll
    for (int r = 0; r < 4; ++r)
        #pragma unroll
        for (int c = 0; c < 4; ++c) {
            int m = 16 * r + lrow;
            int col0 = (wave * 4 + c) * 16 + 4 * lkhi;
            *(uint2*)&X[m * 264 + col0] =
                pack4(acc[r][c][0], acc[r][c][1], acc[r][c][2], acc[r][c][3]);
        }
    __syncthreads();

    // P3a: t3 = silu(ea @ pw1 + pb1 (folded)), UNswapped; dp = t3 @ pw2 reg-reduced
    #pragma unroll
    for (int r = 0; r < 4; ++r)
        #pragma unroll
        for (int c = 0; c < 4; ++c) acc[r][c] = (f32x4)0.f;
    mmP<8, false>(X, 0, pw1p, wave, lane, acc);
    extrasStep<false>(EXT, pw1p, 8, wave, lane, acc);
    #pragma unroll
    for (int r = 0; r < 4; ++r) {
        float red[12];
        #pragma unroll
        for (int q = 0; q < 4; ++q) {
            float t3v[4];
            #pragma unroll
            for (int c = 0; c < 4; ++c) t3v[c] = silu_f(acc[r][c][q]);
            #pragma unroll
            for (int x = 0; x < 3; ++x) {
                float s = 0.f;
                #pragma unroll
                for (int c = 0; c < 4; ++c) s += t3v[c] * w2l[c][x];
                red[q * 3 + x] = s;
            }
        }
        #pragma unroll
        for (int i = 0; i < 12; ++i) {
            float v = red[i];
            v += __shfl_xor(v, 1);
            v += __shfl_xor(v, 2);
            v += __shfl_xor(v, 4);
            v += __shfl_xor(v, 8);
            red[i] = v;
        }
        if (lrow == 0) {
            #pragma unroll
            for (int q = 0; q < 4; ++q)
                #pragma unroll
                for (int x = 0; x < 3; ++x)
                    dp_s[wave][16 * r + 4 * lkhi + q][x] = red[q * 3 + x];
        }
    }

    // P3b: q1 = ea @ nw1[256:512], swapped -> fragment chunks (direct to global)
    #pragma unroll
    for (int r = 0; r < 4; ++r)
        #pragma unroll
        for (int c = 0; c < 4; ++c) acc[r][c] = (f32x4)0.f;
    mmP<8, true>(X, 8, nw1p, wave, lane, acc);
    {
        uint2* w = q1f_g + ((size_t)blockIdx.x * 4 + wave) * 1024;
        #pragma unroll
        for (int r = 0; r < 4; ++r)
            #pragma unroll
            for (int c = 0; c < 4; ++c)
                w[(r * 4 + c) * 64 + lane] =
                    pack4(acc[r][c][0], acc[r][c][1], acc[r][c][2], acc[r][c][3]);
    }

    __syncthreads();  // dp_s complete
    if (tid < 192) {
        int row = tid / 3, x = tid - row * 3;
        dp_g[(size_t)(e0 + row) * 3 + x] =
            dp_s[0][row][x] + dp_s[1][row][x] + dp_s[2][row][x] + dp_s[3][row][x];
    }
}

// ---------------- node kernel ----------------
// q1/p1 arrive as fragment chunks (one edge block per node block).
// Stage q1 -> LDS rows 1..64 (b64), halo row 0 via broadcast read of prev
// block's row 63. t4 = silu(p1 + q1[m] + q1[m-1] + nb1); h_out = t4 @ nw2 + nb2.
__global__ __launch_bounds__(256, 4) void node_kernel(
    const float* __restrict__ pos,
    const float* __restrict__ nb1, const float* __restrict__ nb2,
    const bf16x8* __restrict__ nw2p,
    const uint2* __restrict__ q1f_g, const uint2* __restrict__ p1_g,
    const float* __restrict__ dp_g,
    float* __restrict__ h_out, float* __restrict__ pos_out) {
    __shared__ bf16 X[65 * 264];   // row t = q1[n0-1+t] -> t4 rows 0..63 (overlay)

    const int tid = threadIdx.x;
    const int lane = tid & 63, wave = tid >> 6;
    const int lrow = lane & 15, lkhi = lane >> 4;
    const int n0 = blockIdx.x * 64;

    // pos head
    if (tid < 192) {
        int row = tid & 63, col = tid >> 6;
        int i = n0 + row;
        float dpi = (i < NN - 1) ? dp_g[(size_t)i * 3 + col] : 0.f;
        float dpm = (i > 0) ? dp_g[(size_t)(i - 1) * 3 + col] : 0.f;
        pos_out[(size_t)i * 3 + col] = pos[(size_t)i * 3 + col] + 0.1f * (dpi - dpm);
    }

    // p1 chunk loads (kept in regs)
    uint2 p1r[16];
    {
        const uint2* pp = p1_g + ((size_t)blockIdx.x * 4 + wave) * 1024;
        #pragma unroll
        for (int i = 0; i < 16; ++i) p1r[i] = pp[i * 64 + lane];
    }
    // q1 chunks -> LDS rows 1..64 (masked at chain end)
    {
        const uint2* qp = q1f_g + ((size_t)blockIdx.x * 4 + wave) * 1024;
        #pragma unroll
        for (int i = 0; i < 16; ++i) {
            uint2 v = qp[i * 64 + lane];
            int m = 16 * (i >> 2) + lrow;
            if (n0 + m > NN - 2) { v.x = 0u; v.y = 0u; }
            int col0 = (wave * 4 + (i & 3)) * 16 + 4 * lkhi;
            *(uint2*)&X[(m + 1) * 264 + col0] = v;
        }
    }
    // halo row 0 = prev block's q1 row 63 (broadcast reads)
    if (lrow == 0) {
        #pragma unroll
        for (int c = 0; c < 4; ++c) {
            uint2 v; v.x = 0u; v.y = 0u;
            if (blockIdx.x > 0)
                v = q1f_g[((size_t)(blockIdx.x - 1) * 4 + wave) * 1024 + (12 + c) * 64 + (15 + 16 * lkhi)];
            *(uint2*)&X[(wave * 4 + c) * 16 + 4 * lkhi] = v;
        }
    }
    float4 b1v[4];
    #pragma unroll
    for (int c = 0; c < 4; ++c)
        b1v[c] = *(const float4*)&nb1[(wave * 4 + c) * 16 + 4 * lkhi];
    __syncthreads();

    // t4 = silu(p1 + q1[m] + q1[m-1] + nb1) in regs
    uint2 t4p[16];
    #pragma unroll
    for (int i = 0; i < 16; ++i) {
        int m = 16 * (i >> 2) + lrow;
        int col0 = (wave * 4 + (i & 3)) * 16 + 4 * lkhi;
        uint2 qm1 = *(const uint2*)&X[m * 264 + col0];
        uint2 qm  = *(const uint2*)&X[(m + 1) * 264 + col0];
        uint2 p = p1r[i];
        float4 bb = b1v[i & 3];
        float z0 = bfu2f(p.x & 0xffffu) + bfu2f(qm.x & 0xffffu) + bfu2f(qm1.x & 0xffffu) + bb.x;
        float z1 = bfu2f(p.x >> 16)     + bfu2f(qm.x >> 16)     + bfu2f(qm1.x >> 16)     + bb.y;
        float z2 = bfu2f(p.y & 0xffffu) + bfu2f(qm.y & 0xffffu) + bfu2f(qm1.y & 0xffffu) + bb.z;
        float z3 = bfu2f(p.y >> 16)     + bfu2f(qm.y >> 16)     + bfu2f(qm1.y >> 16)     + bb.w;
        t4p[i] = pack4(silu_f(z0), silu_f(z1), silu_f(z2), silu_f(z3));
    }
    __syncthreads();  // all q1 reads done
    #pragma unroll
    for (int i = 0; i < 16; ++i) {
        int m = 16 * (i >> 2) + lrow;
        int col0 = (wave * 4 + (i & 3)) * 16 + 4 * lkhi;
        *(uint2*)&X[m * 264 + col0] = t4p[i];
    }
    __syncthreads();

    // P2: h_out = t4 @ nw2 + nb2 (unswapped, rows 0..63)
    f32x4 acc[4][4];
    #pragma unroll
    for (int r = 0; r < 4; ++r)
        #pragma unroll
        for (int c = 0; c < 4; ++c) acc[r][c] = (f32x4)0.f;
    mmP<8, false>(X, 0, nw2p, wave, lane, acc);
    float b2[4];
    #pragma unroll
    for (int c = 0; c < 4; ++c) b2[c] = nb2[(wave * 4 + c) * 16 + lrow];
    #pragma unroll
    for (int r = 0; r < 4; ++r)
        #pragma unroll
        for (int c = 0; c < 4; ++c)
            #pragma unroll
            for (int q = 0; q < 4; ++q) {
                int row = r * 16 + lkhi * 4 + q;
                int col = (wave * 4 + c) * 16 + lrow;
                h_out[(size_t)(n0 + row) * HD + col] = acc[r][c][q] + b2[c];
            }
}

// ---------------- launch ----------------
extern "C" void kernel_launch(void* const* d_in, const int* in_sizes, int n_in,
                              void* d_out, int out_size, void* d_ws, size_t ws_size,
                              hipStream_t stream) {
    const float* h   = (const float*)d_in[0];
    const float* pos = (const float*)d_in[1];
    const float* ew1 = (const float*)d_in[2];
    const float* eb1 = (const float*)d_in[3];
    const float* ew2 = (const float*)d_in[4];
    const float* eb2 = (const float*)d_in[5];
    const float* pw1 = (const float*)d_in[6];
    const float* pb1 = (const float*)d_in[7];
    const float* pw2 = (const float*)d_in[8];
    const float* nw1 = (const float*)d_in[9];
    const float* nb1 = (const float*)d_in[10];
    const float* nw2 = (const float*)d_in[11];
    const float* nb2 = (const float*)d_in[12];

    char* ws = (char*)d_ws;
    uint2* q1f  = (uint2*)ws;                     // 67108864 B
    float* dp   = (float*)(ws + 67108864);        // 1572864 B
    uint2* p1   = (uint2*)(ws + 68681728);        // 67108864 B
    char*  wsw = ws + 135790592;
    bf16*  ew1p = (bf16*)(wsw);                   // 278528 B (17 ks)
    bf16*  ew2p = (bf16*)(wsw + 278528);          // 147456 B (9 ks)
    bf16*  pw1p = (bf16*)(wsw + 425984);          // 147456 B (9 ks)
    bf16*  nw1p = (bf16*)(wsw + 573440);          // 262144 B (16 ks)
    bf16*  nw2p = (bf16*)(wsw + 835584);          // 131072 B (8 ks)

    float* out = (float*)d_out;
    float* h_out = out;
    float* pos_out = out + (size_t)NN * HD;

    pack_kernel<<<1888, 256, 0, stream>>>(ew1, eb1, ew2, eb2, pw1, pb1, nw1, nw2,
                                          ew1p, ew2p, pw1p, nw1p, nw2p);
    edge_kernel<<<2048, 256, 0, stream>>>(h, pos, pw2,
                                          (const bf16x8*)ew1p, (const bf16x8*)ew2p,
                                          (const bf16x8*)pw1p, (const bf16x8*)nw1p,
                                          q1f, p1, dp);
    node_kernel<<<2048, 256, 0, stream>>>(pos, nb1, nb2,
                                          (const bf16x8*)nw2p,
                                          (const uint2*)q1f, (const uint2*)p1, dp,
                                          h_out, pos_out);
}

// Round 10
// 275.177 us; speedup vs baseline: 1.0225x; 1.0225x over previous
//
#include <hip/hip_runtime.h>
#include <hip/hip_bf16.h>
#include <math.h>

#define NN 131072
#define HD 256

typedef __bf16 bf16;
typedef __attribute__((ext_vector_type(8))) __bf16 bf16x8;
typedef __attribute__((ext_vector_type(4))) __bf16 bf16x4;
typedef __attribute__((ext_vector_type(4))) float f32x4;

__device__ __forceinline__ float silu_f(float x) { return x / (1.f + __expf(-x)); }

__device__ __forceinline__ float bfu2f(unsigned int lo16) {
    unsigned int u = lo16 << 16;
    return __builtin_bit_cast(float, u);
}
__device__ __forceinline__ unsigned short f2bfu(float f) {
    bf16 b = (bf16)f;
    return __builtin_bit_cast(unsigned short, b);
}
__device__ __forceinline__ uint2 pack4(float a, float b, float c, float d) {
    uint2 v;
    v.x = (unsigned int)f2bfu(a) | ((unsigned int)f2bfu(b) << 16);
    v.y = (unsigned int)f2bfu(c) | ((unsigned int)f2bfu(d) << 16);
    return v;
}

// GEMM over 64-row LDS A-tile (stride 264) x packed-B, 2-deep B prefetch.
// SWAP=false: mfma(X,W) -> lane holds (m = 16r+4lkhi+q, n = 16(4w+c)+lrow)
// SWAP=true:  mfma(W,X) -> lane holds (n = 16(4w+c)+4lkhi+q, m = 16r+lrow)
template<int KS, bool SWAP>
__device__ __forceinline__ void mmP(const bf16* Xl, int bk0, const bf16x8* __restrict__ Bp,
                                    int wave, int lane, f32x4 acc[4][4]) {
    const int lrow = lane & 15, lkhi = lane >> 4;
    bf16x8 bcur[4], bnxt[4];
    #pragma unroll
    for (int c = 0; c < 4; ++c)
        bcur[c] = Bp[(bk0 * 16 + wave * 4 + c) * 64 + lane];
    #pragma unroll
    for (int ks = 0; ks < KS; ++ks) {
        if (ks + 1 < KS) {
            #pragma unroll
            for (int c = 0; c < 4; ++c)
                bnxt[c] = Bp[((bk0 + ks + 1) * 16 + wave * 4 + c) * 64 + lane];
        }
        bf16x8 a[4];
        #pragma unroll
        for (int r = 0; r < 4; ++r)
            a[r] = *(const bf16x8*)&Xl[(r * 16 + lrow) * 264 + ks * 32 + lkhi * 8];
        #pragma unroll
        for (int c = 0; c < 4; ++c)
            #pragma unroll
            for (int r = 0; r < 4; ++r)
                acc[r][c] = SWAP
                    ? __builtin_amdgcn_mfma_f32_16x16x32_bf16(bcur[c], a[r], acc[r][c], 0, 0, 0)
                    : __builtin_amdgcn_mfma_f32_16x16x32_bf16(a[r], bcur[c], acc[r][c], 0, 0, 0);
        #pragma unroll
        for (int c = 0; c < 4; ++c) bcur[c] = bnxt[c];
    }
}

// ---------------- weight packing ----------------
__device__ __forceinline__ void packW(const float* __restrict__ W, bf16* __restrict__ P, int idx) {
    int j  = idx & 7;
    int ln = (idx >> 3) & 63;
    int cb = (idx >> 9) & 15;
    int ks = idx >> 13;
    int k = ks * 32 + ((ln >> 4) << 3) + j;
    int n = (cb << 4) + (ln & 15);
    P[idx] = (bf16)W[k * HD + n];
}

__global__ void pack_kernel(const float* __restrict__ ew1, const float* __restrict__ ew2,
                            const float* __restrict__ pw1, const float* __restrict__ nw1,
                            const float* __restrict__ nw2,
                            bf16* __restrict__ ew1p, bf16* __restrict__ ew2p,
                            bf16* __restrict__ pw1p, bf16* __restrict__ nw1p,
                            bf16* __restrict__ nw2p) {
    int t = blockIdx.x * 256 + threadIdx.x;
    if (t < 131072) { packW(ew1, ew1p, t); return; }
    t -= 131072;
    if (t < 65536)  { packW(ew2, ew2p, t); return; }
    t -= 65536;
    if (t < 65536)  { packW(pw1, pw1p, t); return; }
    t -= 65536;
    if (t < 131072) { packW(nw1, nw1p, t); return; }
    t -= 131072;
    if (t < 65536)  { packW(nw2, nw2p, t); return; }
}

// ---------------- edge kernel ----------------
// 64 edges/block, (256,3). Swapped MFMA + b64 epilogues for t1/ea/q1;
// everything else identical to the R7 baseline.
__global__ __launch_bounds__(256, 3) void edge_kernel(
    const float* __restrict__ h, const float* __restrict__ pos,
    const float* __restrict__ ew1, const float* __restrict__ eb1,
    const float* __restrict__ eb2, const float* __restrict__ pb1,
    const float* __restrict__ pw2,
    const bf16x8* __restrict__ ew1p, const bf16x8* __restrict__ ew2p,
    const bf16x8* __restrict__ pw1p, const bf16x8* __restrict__ nw1p,
    bf16* __restrict__ q1_g, uint2* __restrict__ p1_g,
    float* __restrict__ dp_g) {
    __shared__ bf16 X[65 * 264];          // h rows -> t1 -> ea -> q1 (in place)
    __shared__ float dist_s[64];
    __shared__ float dp_s[4][64][3];

    const int tid = threadIdx.x;
    const int lane = tid & 63, wave = tid >> 6;
    const int lrow = lane & 15, lkhi = lane >> 4;
    const int e0 = blockIdx.x * 64;

    // stage h rows e0..e0+64 (bf16)
    for (int idx = tid; idx < 65 * 64; idx += 256) {
        int r = idx >> 6, c4 = (idx & 63) << 2;
        int gr = e0 + r;
        float4 v = make_float4(0.f, 0.f, 0.f, 0.f);
        if (gr < NN) v = *(const float4*)&h[(size_t)gr * HD + c4];
        bf16x4 b;
        b[0] = (bf16)v.x; b[1] = (bf16)v.y; b[2] = (bf16)v.z; b[3] = (bf16)v.w;
        *(bf16x4*)&X[r * 264 + c4] = b;
    }
    if (tid < 64) {
        int e = e0 + tid;
        float d = 0.f;
        if (e < NN - 1) {
            float dx = pos[3 * e + 3] - pos[3 * e];
            float dy = pos[3 * e + 4] - pos[3 * e + 1];
            float dz = pos[3 * e + 5] - pos[3 * e + 2];
            d = sqrtf(dx * dx + dy * dy + dz * dz);
        }
        dist_s[tid] = d;
    }
    // hoisted params for P3a (unswapped layout: n = 16(4w+c)+lrow)
    float bias3[4], w2l[4][3];
    #pragma unroll
    for (int c = 0; c < 4; ++c) {
        int n = (wave * 4 + c) * 16 + lrow;
        bias3[c] = pb1[n];
        #pragma unroll
        for (int x = 0; x < 3; ++x) w2l[c][x] = pw2[n * 3 + x];
    }
    __syncthreads();

    f32x4 acc[4][4];

    // P0: p1 = h @ nw1[:256] (UNswapped, R7-exact) -> uint2 fragment chunks
    #pragma unroll
    for (int r = 0; r < 4; ++r)
        #pragma unroll
        for (int c = 0; c < 4; ++c) acc[r][c] = (f32x4)0.f;
    mmP<8, false>(X, 0, nw1p, wave, lane, acc);
    {
        uint2* w = p1_g + ((size_t)blockIdx.x * 4 + wave) * 1024;
        #pragma unroll
        for (int r = 0; r < 4; ++r)
            #pragma unroll
            for (int c = 0; c < 4; ++c)
                w[(r * 4 + c) * 64 + lane] =
                    pack4(acc[r][c][0], acc[r][c][1], acc[r][c][2], acc[r][c][3]);
    }

    // P1: t1 = silu(edge_feat @ ew1 + eb1 + dist*ew1[512]); SWAPPED, 16 ks (rb trick)
    #pragma unroll
    for (int r = 0; r < 4; ++r)
        #pragma unroll
        for (int c = 0; c < 4; ++c) acc[r][c] = (f32x4)0.f;
    {
        bf16x8 bcur[4], bnxt[4];
        #pragma unroll
        for (int c = 0; c < 4; ++c)
            bcur[c] = ew1p[(wave * 4 + c) * 64 + lane];
        #pragma unroll
        for (int ks = 0; ks < 16; ++ks) {
            if (ks < 15) {
                #pragma unroll
                for (int c = 0; c < 4; ++c)
                    bnxt[c] = ew1p[((ks + 1) * 16 + wave * 4 + c) * 64 + lane];
            }
            const int rb = (ks >= 8) ? 1 : 0;
            const int kk = ks * 32 + lkhi * 8 - rb * 256;
            bf16x8 a[4];
            #pragma unroll
            for (int r = 0; r < 4; ++r)
                a[r] = *(const bf16x8*)&X[(r * 16 + lrow + rb) * 264 + kk];
            #pragma unroll
            for (int c = 0; c < 4; ++c)
                #pragma unroll
                for (int r = 0; r < 4; ++r)
                    acc[r][c] = __builtin_amdgcn_mfma_f32_16x16x32_bf16(bcur[c], a[r], acc[r][c], 0, 0, 0);
            #pragma unroll
            for (int c = 0; c < 4; ++c) bcur[c] = bnxt[c];
        }
    }
    __syncthreads();  // all P0/P1 reads of X done
    // epi1 (swapped layout): m = 16r+lrow, cols col0..col0+3
    #pragma unroll
    for (int r = 0; r < 4; ++r)
        #pragma unroll
        for (int c = 0; c < 4; ++c) {
            int m = 16 * r + lrow;
            int col0 = (wave * 4 + c) * 16 + 4 * lkhi;
            float4 bb = *(const float4*)&eb1[col0];
            float4 wl = *(const float4*)&ew1[512 * HD + col0];
            float d = dist_s[m];
            *(uint2*)&X[m * 264 + col0] =
                pack4(silu_f(acc[r][c][0] + d * wl.x + bb.x),
                      silu_f(acc[r][c][1] + d * wl.y + bb.y),
                      silu_f(acc[r][c][2] + d * wl.z + bb.z),
                      silu_f(acc[r][c][3] + d * wl.w + bb.w));
        }
    __syncthreads();

    // P2: ea = t1 @ ew2 + eb2; SWAPPED
    #pragma unroll
    for (int r = 0; r < 4; ++r)
        #pragma unroll
        for (int c = 0; c < 4; ++c) acc[r][c] = (f32x4)0.f;
    mmP<8, true>(X, 0, ew2p, wave, lane, acc);
    __syncthreads();
    #pragma unroll
    for (int r = 0; r < 4; ++r)
        #pragma unroll
        for (int c = 0; c < 4; ++c) {
            int m = 16 * r + lrow;
            int col0 = (wave * 4 + c) * 16 + 4 * lkhi;
            float4 bb = *(const float4*)&eb2[col0];
            *(uint2*)&X[m * 264 + col0] =
                pack4(acc[r][c][0] + bb.x, acc[r][c][1] + bb.y,
                      acc[r][c][2] + bb.z, acc[r][c][3] + bb.w);
        }
    __syncthreads();

    // P3a: t3 = silu(ea @ pw1 + pb1), UNswapped; dp = t3 @ pw2 reg-reduced (R7-exact)
    #pragma unroll
    for (int r = 0; r < 4; ++r)
        #pragma unroll
        for (int c = 0; c < 4; ++c) acc[r][c] = (f32x4)0.f;
    mmP<8, false>(X, 0, pw1p, wave, lane, acc);
    #pragma unroll
    for (int r = 0; r < 4; ++r) {
        float red[12];
        #pragma unroll
        for (int q = 0; q < 4; ++q) {
            float t3v[4];
            #pragma unroll
            for (int c = 0; c < 4; ++c) t3v[c] = silu_f(acc[r][c][q] + bias3[c]);
            #pragma unroll
            for (int x = 0; x < 3; ++x) {
                float s = 0.f;
                #pragma unroll
                for (int c = 0; c < 4; ++c) s += t3v[c] * w2l[c][x];
                red[q * 3 + x] = s;
            }
        }
        #pragma unroll
        for (int i = 0; i < 12; ++i) {
            float v = red[i];
            v += __shfl_xor(v, 1);
            v += __shfl_xor(v, 2);
            v += __shfl_xor(v, 4);
            v += __shfl_xor(v, 8);
            red[i] = v;
        }
        if (lrow == 0) {
            #pragma unroll
            for (int q = 0; q < 4; ++q)
                #pragma unroll
                for (int x = 0; x < 3; ++x)
                    dp_s[wave][16 * r + 4 * lkhi + q][x] = red[q * 3 + x];
        }
    }

    // P3b: q1 = ea @ nw1[256:512]; SWAPPED (same X state as P3a — no barrier)
    #pragma unroll
    for (int r = 0; r < 4; ++r)
        #pragma unroll
        for (int c = 0; c < 4; ++c) acc[r][c] = (f32x4)0.f;
    mmP<8, true>(X, 8, nw1p, wave, lane, acc);

    __syncthreads();  // all X reads done + dp_s visible
    // overlay X = q1 (vector b64 stores)
    #pragma unroll
    for (int r = 0; r < 4; ++r)
        #pragma unroll
        for (int c = 0; c < 4; ++c) {
            int m = 16 * r + lrow;
            int col0 = (wave * 4 + c) * 16 + 4 * lkhi;
            *(uint2*)&X[m * 264 + col0] =
                pack4(acc[r][c][0], acc[r][c][1], acc[r][c][2], acc[r][c][3]);
        }
    if (tid < 192) {
        int row = tid / 3, x = tid - row * 3;
        float s = dp_s[0][row][x] + dp_s[1][row][x] + dp_s[2][row][x] + dp_s[3][row][x];
        dp_g[(size_t)(e0 + row) * 3 + x] = s;
    }
    __syncthreads();
    // q1 -> global (row layout, coalesced) — R7-exact
    for (int idx = tid; idx < 64 * 128; idx += 256) {
        int r = idx >> 7, cu = idx & 127;
        ((unsigned int*)&q1_g[(size_t)(e0 + r) * HD])[cu] = ((const unsigned int*)&X[r * 264])[cu];
    }
}

// ---------------- node kernel (R7-exact) ----------------
__global__ __launch_bounds__(256, 4) void node_kernel(
    const float* __restrict__ pos,
    const float* __restrict__ nb1, const float* __restrict__ nb2,
    const bf16x8* __restrict__ nw2p,
    const bf16* __restrict__ q1_g, const uint2* __restrict__ p1_g,
    const float* __restrict__ dp_g,
    float* __restrict__ h_out, float* __restrict__ pos_out) {
    __shared__ bf16 X[65 * 264];   // q1 halo (slot t = q1[n0-1+t]) -> t4 rows 0..63

    const int tid = threadIdx.x;
    const int lane = tid & 63, wave = tid >> 6;
    const int lrow = lane & 15, lkhi = lane >> 4;
    const int n0 = blockIdx.x * 64;

    // pos head
    if (tid < 192) {
        int row = tid & 63, col = tid >> 6;
        int i = n0 + row;
        float dpi = (i < NN - 1) ? dp_g[(size_t)i * 3 + col] : 0.f;
        float dpm = (i > 0) ? dp_g[(size_t)(i - 1) * 3 + col] : 0.f;
        pos_out[(size_t)i * 3 + col] = pos[(size_t)i * 3 + col] + 0.1f * (dpi - dpm);
    }

    // stage q1 halo, uint4-vectorized
    for (int idx = tid; idx < 65 * 32; idx += 256) {
        int t = idx >> 5, cu = idx & 31;
        int er = n0 - 1 + t;
        uint4 v = make_uint4(0u, 0u, 0u, 0u);
        if (er >= 0 && er <= NN - 2) v = ((const uint4*)&q1_g[(size_t)er * HD])[cu];
        ((uint4*)&X[t * 264])[cu] = v;
    }
    // early p1 fragment loads (coalesced uint2)
    uint2 p1r[16];
    {
        const uint2* p1p = p1_g + ((size_t)blockIdx.x * 4 + wave) * 1024;
        #pragma unroll
        for (int i = 0; i < 16; ++i) p1r[i] = p1p[i * 64 + lane];
    }
    float b1[4];
    #pragma unroll
    for (int c = 0; c < 4; ++c) b1[c] = nb1[(wave * 4 + c) * 16 + lrow];
    __syncthreads();

    // elementwise t4 = silu(p1 + q1[i] + q1[i-1] + b1), held in regs
    unsigned int t4p[32];
    #pragma unroll
    for (int r = 0; r < 4; ++r)
        #pragma unroll
        for (int c = 0; c < 4; ++c) {
            int i = r * 4 + c;
            int col = (wave * 4 + c) * 16 + lrow;
            #pragma unroll
            for (int qh = 0; qh < 2; ++qh) {
                unsigned int pk = qh == 0 ? p1r[i].x : p1r[i].y;
                unsigned int outp = 0;
                #pragma unroll
                for (int j = 0; j < 2; ++j) {
                    int q = 2 * qh + j;
                    int row = r * 16 + lkhi * 4 + q;
                    float p1v = bfu2f(j == 0 ? (pk & 0xffffu) : (pk >> 16));
                    float z = p1v + (float)X[(row + 1) * 264 + col] + (float)X[row * 264 + col] + b1[c];
                    unsigned short tb = f2bfu(silu_f(z));
                    outp |= (unsigned int)tb << (16 * j);
                }
                t4p[i * 2 + qh] = outp;
            }
        }
    __syncthreads();  // all q1 reads done
    // write t4 tile (rows 0..63)
    #pragma unroll
    for (int r = 0; r < 4; ++r)
        #pragma unroll
        for (int c = 0; c < 4; ++c) {
            int i = r * 4 + c;
            int col = (wave * 4 + c) * 16 + lrow;
            #pragma unroll
            for (int q = 0; q < 4; ++q) {
                int row = r * 16 + lkhi * 4 + q;
                unsigned int pk = t4p[i * 2 + (q >> 1)];
                unsigned short tb = (unsigned short)((q & 1) ? (pk >> 16) : (pk & 0xffffu));
                X[row * 264 + col] = __builtin_bit_cast(bf16, tb);
            }
        }
    __syncthreads();

    // P2: h_out = t4 @ nw2 + nb2
    f32x4 acc[4][4];
    #pragma unroll
    for (int r = 0; r < 4; ++r)
        #pragma unroll
        for (int c = 0; c < 4; ++c) acc[r][c] = (f32x4)0.f;
    mmP<8, false>(X, 0, nw2p, wave, lane, acc);
    float b2[4];
    #pragma unroll
    for (int c = 0; c < 4; ++c) b2[c] = nb2[(wave * 4 + c) * 16 + lrow];
    #pragma unroll
    for (int r = 0; r < 4; ++r)
        #pragma unroll
        for (int c = 0; c < 4; ++c)
            #pragma unroll
            for (int q = 0; q < 4; ++q) {
                int row = r * 16 + lkhi * 4 + q;
                int col = (wave * 4 + c) * 16 + lrow;
                h_out[(size_t)(n0 + row) * HD + col] = acc[r][c][q] + b2[c];
            }
}

// ---------------- launch ----------------
extern "C" void kernel_launch(void* const* d_in, const int* in_sizes, int n_in,
                              void* d_out, int out_size, void* d_ws, size_t ws_size,
                              hipStream_t stream) {
    const float* h   = (const float*)d_in[0];
    const float* pos = (const float*)d_in[1];
    const float* ew1 = (const float*)d_in[2];
    const float* eb1 = (const float*)d_in[3];
    const float* ew2 = (const float*)d_in[4];
    const float* eb2 = (const float*)d_in[5];
    const float* pw1 = (const float*)d_in[6];
    const float* pb1 = (const float*)d_in[7];
    const float* pw2 = (const float*)d_in[8];
    const float* nw1 = (const float*)d_in[9];
    const float* nb1 = (const float*)d_in[10];
    const float* nw2 = (const float*)d_in[11];
    const float* nb2 = (const float*)d_in[12];

    char* ws = (char*)d_ws;
    bf16*  q1   = (bf16*)ws;                      // 67108864 B
    float* dp   = (float*)(ws + 67108864);        // 1572864 B
    uint2* p1   = (uint2*)(ws + 68681728);        // 67108864 B
    char*  wsw = ws + 135790592;
    bf16*  ew1p = (bf16*)(wsw);                   // 262144 B
    bf16*  ew2p = (bf16*)(wsw + 262144);          // 131072 B
    bf16*  pw1p = (bf16*)(wsw + 393216);          // 131072 B
    bf16*  nw1p = (bf16*)(wsw + 524288);          // 262144 B
    bf16*  nw2p = (bf16*)(wsw + 786432);          // 131072 B

    float* out = (float*)d_out;
    float* h_out = out;
    float* pos_out = out + (size_t)NN * HD;

    pack_kernel<<<1792, 256, 0, stream>>>(ew1, ew2, pw1, nw1, nw2,
                                          ew1p, ew2p, pw1p, nw1p, nw2p);
    edge_kernel<<<2048, 256, 0, stream>>>(h, pos, ew1, eb1, eb2, pb1, pw2,
                                          (const bf16x8*)ew1p, (const bf16x8*)ew2p,
                                          (const bf16x8*)pw1p, (const bf16x8*)nw1p,
                                          q1, p1, dp);
    node_kernel<<<2048, 256, 0, stream>>>(pos, nb1, nb2,
                                          (const bf16x8*)nw2p,
                                          q1, (const uint2*)p1, dp, h_out, pos_out);
}